// Round 5
// baseline (399.551 us; speedup 1.0000x reference)
//
#include <hip/hip_runtime.h>

#define N_NODES 100000
#define N_EDGES 800000
#define N_IN    256
#define N_H     128
#define M_TOT   (2 * N_NODES)   // 200000; 16 | 100000 so waves never straddle branches
#define HB_ROW  256             // interleaved: [node][ h1(128) | h2(128) ] bf16

typedef __bf16 bfx8 __attribute__((ext_vector_type(8)));
typedef unsigned short u16x8 __attribute__((ext_vector_type(8)));
typedef float fx4 __attribute__((ext_vector_type(4)));

__device__ inline unsigned short f2bf(float f) {
    union { float f; unsigned u; } v; v.f = f;
    return (unsigned short)((v.u + 0x7FFF + ((v.u >> 16) & 1)) >> 16);  // RNE
}
__device__ inline float bf2f(unsigned short s) {
    union { unsigned u; float f; } v; v.u = ((unsigned)s) << 16;
    return v.f;
}

// ---------------- bf16-MFMA GEMM, both branches, interleaved output ----------
// 512 thr = 8 waves x 16 rows = 128 rows/block; W^T staged once in LDS.
#define WT_S 264
#define NGB  1563   // ceil(200000/128)

__global__ __launch_bounds__(512, 4) void gemm_kernel(
        const float* __restrict__ x1, const float* __restrict__ x2,
        const unsigned short* __restrict__ wT,     // [N_H][N_IN] bf16 bits
        unsigned short* __restrict__ hb) {         // [N_NODES][HB_ROW] bf16 bits
    __shared__ unsigned short wl[N_H * WT_S];      // 66 KB -> 2 blocks/CU, 16 waves/CU
    const int t = threadIdx.x;
#pragma unroll
    for (int i = 0; i < 8; ++i) {                  // 4096 x 16B, coalesced
        int f  = t + i * 512;
        int n  = f >> 5;
        int kp = (f & 31) * 8;
        *(u16x8*)(wl + n * WT_S + kp) = *(const u16x8*)(wT + n * N_IN + kp);
    }
    __syncthreads();

    const int wave = t >> 6, lane = t & 63;
    const int quad = lane >> 4, l16 = lane & 15;
    const int mw = blockIdx.x * 128 + wave * 16;   // output row base, 0..199999
    if (mw >= M_TOT) return;                       // tail waves (after barrier)
    const int half = (mw < N_NODES) ? 0 : 1;
    const float* x = half ? x2 : x1;
    const int mrow = half ? mw - N_NODES : mw;

    fx4 acc[8];
#pragma unroll
    for (int c = 0; c < 8; ++c) acc[c] = (fx4){0.f, 0.f, 0.f, 0.f};

    const float* xrow = x + (size_t)(mrow + l16) * N_IN;
#pragma unroll
    for (int kk = 0; kk < N_IN; kk += 32) {
        float4 a0 = *(const float4*)(xrow + kk + quad * 8);
        float4 a1 = *(const float4*)(xrow + kk + quad * 8 + 4);
        u16x8 au;
        au[0] = f2bf(a0.x); au[1] = f2bf(a0.y); au[2] = f2bf(a0.z); au[3] = f2bf(a0.w);
        au[4] = f2bf(a1.x); au[5] = f2bf(a1.y); au[6] = f2bf(a1.z); au[7] = f2bf(a1.w);
        bfx8 af = __builtin_bit_cast(bfx8, au);
#pragma unroll
        for (int c = 0; c < 8; ++c) {
            bfx8 bf = *(const bfx8*)(wl + (size_t)(c * 16 + l16) * WT_S + kk + quad * 8);
            acc[c] = __builtin_amdgcn_mfma_f32_16x16x32_bf16(af, bf, acc[c], 0, 0, 0);
        }
    }
    // C/D: col = l16, row = quad*4 + reg; write into interleaved half
#pragma unroll
    for (int c = 0; c < 8; ++c)
#pragma unroll
        for (int r = 0; r < 4; ++r)
            hb[(size_t)(mrow + quad * 4 + r) * HB_ROW + half * N_H + c * 16 + l16] =
                f2bf(acc[c][r]);
}

// ------- prep: histogram (3125 blks) + W^T bf16 (32 blks) + wsum (1 blk) -----
#define HIST_BLKS 3125
__global__ __launch_bounds__(256) void prep_kernel(const int* __restrict__ ei,
                                                   int* __restrict__ deg,
                                                   const float* __restrict__ W,
                                                   unsigned short* __restrict__ wT,
                                                   const float* __restrict__ linW,
                                                   const float* __restrict__ linb,
                                                   float* __restrict__ wsum) {
    const int t = threadIdx.x;
    if (blockIdx.x < HIST_BLKS) {
        int e = blockIdx.x * 256 + t;
        if (e < N_EDGES) atomicAdd(deg + ei[e], 1);
    } else if (blockIdx.x < HIST_BLKS + 32) {
        int kb = (blockIdx.x - HIST_BLKS) * 8;
#pragma unroll
        for (int p = 0; p < 4; ++p) {
            int idx = p * 256 + t;
            int k = kb + (idx >> 7), n = idx & 127;
            wT[(size_t)n * N_IN + k] = f2bf(W[(size_t)k * N_H + n]);
        }
    } else {
        int j = t;
        if (j < N_H) {
            float s = 0.f;
            for (int o = 0; o < N_H; ++o) s += linW[j * N_H + o];
            wsum[j] = s;
        }
        if (j == N_H) {
            float s = 0.f;
            for (int o = 0; o < N_H; ++o) s += linb[o];
            wsum[N_H] = s;
        }
    }
}

// ---------------- scans ------------------------------------------------------
__global__ __launch_bounds__(256) void scan1_kernel(const int* __restrict__ deg,
                                                    int* __restrict__ part,
                                                    int* __restrict__ bsum) {
    __shared__ int s[256];
    int g = blockIdx.x * 256 + threadIdx.x;
    int v = (g < N_NODES) ? deg[g] : 0;
    s[threadIdx.x] = v;
    __syncthreads();
#pragma unroll
    for (int off = 1; off < 256; off <<= 1) {
        int t = (threadIdx.x >= off) ? s[threadIdx.x - off] : 0;
        __syncthreads();
        s[threadIdx.x] += t;
        __syncthreads();
    }
    if (g < N_NODES) part[g] = s[threadIdx.x] - v;    // exclusive within block
    if (threadIdx.x == 255) bsum[blockIdx.x] = s[255]; // block total
}

#define NBLK_SCAN 391
// scan3 computes its own bsum prefix (<=391 adds) -> no separate scan2 pass
__global__ __launch_bounds__(256) void scan3_kernel(const int* __restrict__ part,
                                                    const int* __restrict__ bsum,
                                                    int* __restrict__ off,
                                                    int* __restrict__ cursor) {
    __shared__ int red[256];
    const int t = threadIdx.x;
    int acc = 0;
    for (int j = t; j < (int)blockIdx.x; j += 256) acc += bsum[j];
    red[t] = acc;
    __syncthreads();
#pragma unroll
    for (int o = 128; o; o >>= 1) {
        if (t < o) red[t] += red[t + o];
        __syncthreads();
    }
    const int prefix = red[0];
    int g = blockIdx.x * 256 + t;
    if (g < N_NODES) {
        int o = part[g] + prefix;
        off[g] = o;
        cursor[g] = o;
    }
    if (g == 0) off[N_NODES] = N_EDGES;
}

// ---------------- scatter: edges -> CSR slots (col*HB_ROW premultiplied) -----
__global__ __launch_bounds__(256) void scatter_kernel(const int* __restrict__ ei,
                                                      const float* __restrict__ ew,
                                                      int* __restrict__ cursor,
                                                      int2* __restrict__ edata) {
    int e = blockIdx.x * 256 + threadIdx.x;
    if (e >= N_EDGES) return;
    int row = ei[e];
    int pos = atomicAdd(cursor + row, 1);
    edata[pos] = make_int2(ei[N_EDGES + e] * HB_ROW, __float_as_int(ew[e]));
}

// ------- fused segment-sum SPMM + bias + PReLU + wsum-dot, BOTH branches -----
// one wave per node; half-wave per branch, 4 features/lane (ushort4 = 8B);
// one edge = one contiguous 512B wave gather. 4-edge unroll: 4 gathers in flight.
__global__ __launch_bounds__(256) void gcn_seg_kernel(const int* __restrict__ off,
                                                      const int2* __restrict__ edata,
                                                      const unsigned short* __restrict__ hb,
                                                      const float* __restrict__ gcn_bias,
                                                      const float* __restrict__ prelu_a,
                                                      const float* __restrict__ wsum,
                                                      float* __restrict__ zout) {
    const int wave = threadIdx.x >> 6, lane = threadIdx.x & 63;
    const int node = blockIdx.x * 4 + wave;        // 0..99999
    const int half = lane >> 5;                    // 0: branch1, 1: branch2
    const int fl   = (lane & 31) * 4;              // feature base (0..124)
    const int o8   = half * N_H + fl;              // short offset within row
    const int s = __builtin_amdgcn_readfirstlane(off[node]);
    const int e = __builtin_amdgcn_readfirstlane(off[node + 1]);
    float p0 = 0.f, p1 = 0.f, p2 = 0.f, p3 = 0.f;  // acc set A
    float q0 = 0.f, q1 = 0.f, q2 = 0.f, q3 = 0.f;  // acc set B
    int i = s;
    for (; i + 4 <= e; i += 4) {
        int2 E0 = edata[i], E1 = edata[i + 1], E2 = edata[i + 2], E3 = edata[i + 3];
        ushort4 h0 = *(const ushort4*)(hb + E0.x + o8);
        ushort4 h1 = *(const ushort4*)(hb + E1.x + o8);
        ushort4 h2 = *(const ushort4*)(hb + E2.x + o8);
        ushort4 h3 = *(const ushort4*)(hb + E3.x + o8);
        float w0 = __int_as_float(E0.y), w1 = __int_as_float(E1.y);
        float w2 = __int_as_float(E2.y), w3 = __int_as_float(E3.y);
        p0 += w0 * bf2f(h0.x) + w1 * bf2f(h1.x);
        p1 += w0 * bf2f(h0.y) + w1 * bf2f(h1.y);
        p2 += w0 * bf2f(h0.z) + w1 * bf2f(h1.z);
        p3 += w0 * bf2f(h0.w) + w1 * bf2f(h1.w);
        q0 += w2 * bf2f(h2.x) + w3 * bf2f(h3.x);
        q1 += w2 * bf2f(h2.y) + w3 * bf2f(h3.y);
        q2 += w2 * bf2f(h2.z) + w3 * bf2f(h3.z);
        q3 += w2 * bf2f(h2.w) + w3 * bf2f(h3.w);
    }
    for (; i < e; ++i) {
        int2 E0 = edata[i];
        float w0 = __int_as_float(E0.y);
        ushort4 h0 = *(const ushort4*)(hb + E0.x + o8);
        p0 += w0 * bf2f(h0.x);
        p1 += w0 * bf2f(h0.y);
        p2 += w0 * bf2f(h0.z);
        p3 += w0 * bf2f(h0.w);
    }
    p0 += q0; p1 += q1; p2 += q2; p3 += q3;

    const float alpha = prelu_a[0];
    float4 gb4 = *(const float4*)(gcn_bias + fl);
    float4 ws4 = *(const float4*)(wsum + fl);
    float v0 = p0 + gb4.x, v1 = p1 + gb4.y, v2 = p2 + gb4.z, v3 = p3 + gb4.w;
    v0 = (v0 >= 0.f) ? v0 : alpha * v0;
    v1 = (v1 >= 0.f) ? v1 : alpha * v1;
    v2 = (v2 >= 0.f) ? v2 : alpha * v2;
    v3 = (v3 >= 0.f) ? v3 : alpha * v3;
    float sres = v0 * ws4.x + v1 * ws4.y + v2 * ws4.z + v3 * ws4.w;
#pragma unroll
    for (int o = 16; o; o >>= 1) sres += __shfl_down(sres, o, 32);  // within half
    if ((lane & 31) == 0)
        zout[node + half * N_NODES] = sres + wsum[128];  // wsum[128] = b_sum
}

extern "C" void kernel_launch(void* const* d_in, const int* in_sizes, int n_in,
                              void* d_out, int out_size, void* d_ws, size_t ws_size,
                              hipStream_t stream) {
    const float* x1 = (const float*)d_in[0];
    const float* x2 = (const float*)d_in[1];
    const int*   ei = (const int*)d_in[2];
    const float* ew = (const float*)d_in[3];
    const float* Wg = (const float*)d_in[4];
    const float* gb = (const float*)d_in[5];
    const float* pa = (const float*)d_in[6];
    const float* lW = (const float*)d_in[7];
    const float* lb = (const float*)d_in[8];
    float* zout = (float*)d_out;

    unsigned short* hb   = (unsigned short*)d_ws;               // 25.6M u16 (51.2MB)
    int2*  edata  = (int2*)(hb + (size_t)N_NODES * HB_ROW);     // 800k int2 (6.4MB)
    unsigned short* wT   = (unsigned short*)(edata + N_EDGES);  // 32768 u16
    int*   deg    = (int*)(wT + N_IN * N_H);                    // 100096 i
    int*   part   = deg + 100096;
    int*   off    = part + 100096;                              // uses 100001
    int*   cursor = off + 100096;
    int*   bsum   = cursor + 100096;                            // 512 i
    float* wsum   = (float*)(bsum + 512);                       // 129 f

    hipMemsetAsync(deg, 0, (size_t)N_NODES * sizeof(int), stream);
    prep_kernel<<<HIST_BLKS + 33, 256, 0, stream>>>(ei, deg, Wg, wT, lW, lb, wsum);
    scan1_kernel<<<NBLK_SCAN, 256, 0, stream>>>(deg, part, bsum);
    scan3_kernel<<<NBLK_SCAN, 256, 0, stream>>>(part, bsum, off, cursor);
    scatter_kernel<<<(N_EDGES + 255) / 256, 256, 0, stream>>>(ei, ew, cursor, edata);
    gemm_kernel<<<NGB, 512, 0, stream>>>(x1, x2, wT, hb);
    gcn_seg_kernel<<<N_NODES / 4, 256, 0, stream>>>(off, edata, hb, gb, pa, wsum, zout);
}

// Round 6
// 399.240 us; speedup vs baseline: 1.0008x; 1.0008x over previous
//
#include <hip/hip_runtime.h>

#define N_NODES 100000
#define N_EDGES 800000
#define N_IN    256
#define N_H     128
#define M_TOT   (2 * N_NODES)   // 200000; 16 | 100000 so waves never straddle branches
#define HB_ROW  256             // interleaved: [node][ h1(128) | h2(128) ] bf16
#define E_PAD   1200000         // max padded edges: 800000 + 4*100000

typedef __bf16 bfx8 __attribute__((ext_vector_type(8)));
typedef unsigned short u16x8 __attribute__((ext_vector_type(8)));
typedef float fx4 __attribute__((ext_vector_type(4)));

__device__ inline unsigned short f2bf(float f) {
    union { float f; unsigned u; } v; v.f = f;
    return (unsigned short)((v.u + 0x7FFF + ((v.u >> 16) & 1)) >> 16);  // RNE
}
__device__ inline float bf2f(unsigned short s) {
    union { unsigned u; float f; } v; v.u = ((unsigned)s) << 16;
    return v.f;
}

// ---------------- bf16-MFMA GEMM, both branches, interleaved output ----------
// 512 thr = 8 waves x 16 rows = 128 rows/block; W^T in LDS, XOR-swizzled
// (64 KB exact, <=2-way banks). Depth-2 software-pipelined x prefetch.
#define NGB 1563   // ceil(200000/128)

__global__ __launch_bounds__(512, 4) void gemm_kernel(
        const float* __restrict__ x1, const float* __restrict__ x2,
        const unsigned short* __restrict__ wT,     // [N_H][N_IN] bf16 bits
        unsigned short* __restrict__ hb) {         // [N_NODES][HB_ROW] bf16 bits
    __shared__ unsigned short wl[N_H * 256];       // 64 KB -> 2 blocks/CU
    const int t = threadIdx.x;
#pragma unroll
    for (int i = 0; i < 8; ++i) {                  // 4096 x 16B, coalesced
        int f  = t + i * 512;
        int n  = f >> 5;
        int kb = f & 31;
        *(u16x8*)(wl + n * 256 + ((kb ^ (n & 31)) << 3)) =
            *(const u16x8*)(wT + n * N_IN + (kb << 3));
    }
    __syncthreads();

    const int wave = t >> 6, lane = t & 63;
    const int quad = lane >> 4, l16 = lane & 15;
    const int mw = blockIdx.x * 128 + wave * 16;   // output row base, 0..199999
    if (mw >= M_TOT) return;                       // tail waves (after barrier)
    const int half = (mw < N_NODES) ? 0 : 1;
    const float* x = half ? x2 : x1;
    const int mrow = half ? mw - N_NODES : mw;

    fx4 acc[8];
#pragma unroll
    for (int c = 0; c < 8; ++c) acc[c] = (fx4){0.f, 0.f, 0.f, 0.f};

    const float* xrow = x + (size_t)(mrow + l16) * N_IN + quad * 8;

    // depth-2 pipeline: 4 loads in prologue, each iter refills 2 for j+2
    float4 pa0 = *(const float4*)(xrow);
    float4 pb0 = *(const float4*)(xrow + 4);
    float4 pa1 = *(const float4*)(xrow + 32);
    float4 pb1 = *(const float4*)(xrow + 36);
#pragma unroll
    for (int j = 0; j < 8; ++j) {
        float4 a0 = (j & 1) ? pa1 : pa0;
        float4 a1 = (j & 1) ? pb1 : pb0;
        if (j < 6) {
            const float4* nx = (const float4*)(xrow + (j + 2) * 32);
            if (j & 1) { pa1 = nx[0]; pb1 = nx[1]; }
            else       { pa0 = nx[0]; pb0 = nx[1]; }
        }
        u16x8 au;
        au[0] = f2bf(a0.x); au[1] = f2bf(a0.y); au[2] = f2bf(a0.z); au[3] = f2bf(a0.w);
        au[4] = f2bf(a1.x); au[5] = f2bf(a1.y); au[6] = f2bf(a1.z); au[7] = f2bf(a1.w);
        bfx8 af = __builtin_bit_cast(bfx8, au);
        const int kb0 = (j << 2) + quad;           // (kk/8) + quad
#pragma unroll
        for (int c = 0; c < 8; ++c) {
            int n = c * 16 + l16;
            bfx8 bf = *(const bfx8*)(wl + n * 256 + ((kb0 ^ (n & 31)) << 3));
            acc[c] = __builtin_amdgcn_mfma_f32_16x16x32_bf16(af, bf, acc[c], 0, 0, 0);
        }
    }
    // C/D: col = l16, row = quad*4 + reg; write into interleaved half
#pragma unroll
    for (int c = 0; c < 8; ++c)
#pragma unroll
        for (int r = 0; r < 4; ++r)
            hb[(size_t)(mrow + quad * 4 + r) * HB_ROW + half * N_H + c * 16 + l16] =
                f2bf(acc[c][r]);
}

// ------- prep: histogram (3125 blks) + W^T bf16 (32 blks) + wsum (1 blk) -----
#define HIST_BLKS 3125
__global__ __launch_bounds__(256) void prep_kernel(const int* __restrict__ ei,
                                                   int* __restrict__ deg,
                                                   const float* __restrict__ W,
                                                   unsigned short* __restrict__ wT,
                                                   const float* __restrict__ linW,
                                                   const float* __restrict__ linb,
                                                   float* __restrict__ wsum) {
    const int t = threadIdx.x;
    if (blockIdx.x < HIST_BLKS) {
        int e = blockIdx.x * 256 + t;
        if (e < N_EDGES) atomicAdd(deg + ei[e], 1);
    } else if (blockIdx.x < HIST_BLKS + 32) {
        int kb = (blockIdx.x - HIST_BLKS) * 8;
#pragma unroll
        for (int p = 0; p < 4; ++p) {
            int idx = p * 256 + t;
            int k = kb + (idx >> 7), n = idx & 127;
            wT[(size_t)n * N_IN + k] = f2bf(W[(size_t)k * N_H + n]);
        }
    } else {
        int j = t;
        if (j < N_H) {
            float s = 0.f;
            for (int o = 0; o < N_H; ++o) s += linW[j * N_H + o];
            wsum[j] = s;
        }
        if (j == N_H) {
            float s = 0.f;
            for (int o = 0; o < N_H; ++o) s += linb[o];
            wsum[N_H] = s;
        }
    }
}

// ---------------- scans over 4-PADDED degrees --------------------------------
__global__ __launch_bounds__(256) void scan1_kernel(const int* __restrict__ deg,
                                                    int* __restrict__ part,
                                                    int* __restrict__ bsum) {
    __shared__ int s[256];
    int g = blockIdx.x * 256 + threadIdx.x;
    int v = (g < N_NODES) ? ((deg[g] + 3) & ~3) : 0;   // pad to multiple of 4
    s[threadIdx.x] = v;
    __syncthreads();
#pragma unroll
    for (int off = 1; off < 256; off <<= 1) {
        int t = (threadIdx.x >= off) ? s[threadIdx.x - off] : 0;
        __syncthreads();
        s[threadIdx.x] += t;
        __syncthreads();
    }
    if (g < N_NODES) part[g] = s[threadIdx.x] - v;     // exclusive within block
    if (threadIdx.x == 255) bsum[blockIdx.x] = s[255]; // block total
}

#define NBLK_SCAN 391
// scan3 computes its own bsum prefix (<=391 adds) -> no separate pass
__global__ __launch_bounds__(256) void scan3_kernel(const int* __restrict__ part,
                                                    const int* __restrict__ bsum,
                                                    const int* __restrict__ deg,
                                                    int* __restrict__ off,
                                                    int* __restrict__ cursor) {
    __shared__ int red[256];
    const int t = threadIdx.x;
    int acc = 0;
    for (int j = t; j < (int)blockIdx.x; j += 256) acc += bsum[j];
    red[t] = acc;
    __syncthreads();
#pragma unroll
    for (int o = 128; o; o >>= 1) {
        if (t < o) red[t] += red[t + o];
        __syncthreads();
    }
    const int prefix = red[0];
    int g = blockIdx.x * 256 + t;
    if (g < N_NODES) {
        int o = part[g] + prefix;
        off[g] = o;
        cursor[g] = o;
        if (g == N_NODES - 1) off[N_NODES] = o + ((deg[g] + 3) & ~3);
    }
}

// ---------------- scatter: edges -> padded CSR slots -------------------------
// pad slots stay (0, 0.0f) from the edata memset -> contribute nothing.
__global__ __launch_bounds__(256) void scatter_kernel(const int* __restrict__ ei,
                                                      const float* __restrict__ ew,
                                                      int* __restrict__ cursor,
                                                      int2* __restrict__ edata) {
    int e = blockIdx.x * 256 + threadIdx.x;
    if (e >= N_EDGES) return;
    int row = ei[e];
    int pos = atomicAdd(cursor + row, 1);
    edata[pos] = make_int2(ei[N_EDGES + e] * HB_ROW, __float_as_int(ew[e]));
}

// ------- fused segment-sum SPMM + bias + PReLU + wsum-dot, BOTH branches -----
// one wave per node; half-wave per branch, 4 features/lane (ushort4 = 8B);
// one edge = one contiguous 512B wave gather. Padded segments: exact 4-unroll,
// no remainder, 4 gathers always in flight.
__global__ __launch_bounds__(256) void gcn_seg_kernel(const int* __restrict__ off,
                                                      const int2* __restrict__ edata,
                                                      const unsigned short* __restrict__ hb,
                                                      const float* __restrict__ gcn_bias,
                                                      const float* __restrict__ prelu_a,
                                                      const float* __restrict__ wsum,
                                                      float* __restrict__ zout) {
    const int wave = threadIdx.x >> 6, lane = threadIdx.x & 63;
    const int node = blockIdx.x * 4 + wave;        // 0..99999
    const int half = lane >> 5;                    // 0: branch1, 1: branch2
    const int fl   = (lane & 31) * 4;              // feature base (0..124)
    const int o8   = half * N_H + fl;              // short offset within row
    const int s = __builtin_amdgcn_readfirstlane(off[node]);
    const int e = __builtin_amdgcn_readfirstlane(off[node + 1]);
    float p0 = 0.f, p1 = 0.f, p2 = 0.f, p3 = 0.f;
    float q0 = 0.f, q1 = 0.f, q2 = 0.f, q3 = 0.f;
    for (int i = s; i < e; i += 4) {
        int2 E0 = edata[i], E1 = edata[i + 1], E2 = edata[i + 2], E3 = edata[i + 3];
        ushort4 h0 = *(const ushort4*)(hb + E0.x + o8);
        ushort4 h1 = *(const ushort4*)(hb + E1.x + o8);
        ushort4 h2 = *(const ushort4*)(hb + E2.x + o8);
        ushort4 h3 = *(const ushort4*)(hb + E3.x + o8);
        float w0 = __int_as_float(E0.y), w1 = __int_as_float(E1.y);
        float w2 = __int_as_float(E2.y), w3 = __int_as_float(E3.y);
        p0 += w0 * bf2f(h0.x) + w1 * bf2f(h1.x);
        p1 += w0 * bf2f(h0.y) + w1 * bf2f(h1.y);
        p2 += w0 * bf2f(h0.z) + w1 * bf2f(h1.z);
        p3 += w0 * bf2f(h0.w) + w1 * bf2f(h1.w);
        q0 += w2 * bf2f(h2.x) + w3 * bf2f(h3.x);
        q1 += w2 * bf2f(h2.y) + w3 * bf2f(h3.y);
        q2 += w2 * bf2f(h2.z) + w3 * bf2f(h3.z);
        q3 += w2 * bf2f(h2.w) + w3 * bf2f(h3.w);
    }
    p0 += q0; p1 += q1; p2 += q2; p3 += q3;

    const float alpha = prelu_a[0];
    float4 gb4 = *(const float4*)(gcn_bias + fl);
    float4 ws4 = *(const float4*)(wsum + fl);
    float v0 = p0 + gb4.x, v1 = p1 + gb4.y, v2 = p2 + gb4.z, v3 = p3 + gb4.w;
    v0 = (v0 >= 0.f) ? v0 : alpha * v0;
    v1 = (v1 >= 0.f) ? v1 : alpha * v1;
    v2 = (v2 >= 0.f) ? v2 : alpha * v2;
    v3 = (v3 >= 0.f) ? v3 : alpha * v3;
    float sres = v0 * ws4.x + v1 * ws4.y + v2 * ws4.z + v3 * ws4.w;
#pragma unroll
    for (int o = 16; o; o >>= 1) sres += __shfl_down(sres, o, 32);  // within half
    if ((lane & 31) == 0)
        zout[node + half * N_NODES] = sres + wsum[128];  // wsum[128] = b_sum
}

extern "C" void kernel_launch(void* const* d_in, const int* in_sizes, int n_in,
                              void* d_out, int out_size, void* d_ws, size_t ws_size,
                              hipStream_t stream) {
    const float* x1 = (const float*)d_in[0];
    const float* x2 = (const float*)d_in[1];
    const int*   ei = (const int*)d_in[2];
    const float* ew = (const float*)d_in[3];
    const float* Wg = (const float*)d_in[4];
    const float* gb = (const float*)d_in[5];
    const float* pa = (const float*)d_in[6];
    const float* lW = (const float*)d_in[7];
    const float* lb = (const float*)d_in[8];
    float* zout = (float*)d_out;

    unsigned short* hb   = (unsigned short*)d_ws;               // 25.6M u16 (51.2MB)
    int2*  edata  = (int2*)(hb + (size_t)N_NODES * HB_ROW);     // 1.2M int2 (9.6MB)
    unsigned short* wT   = (unsigned short*)(edata + E_PAD);    // 32768 u16
    int*   deg    = (int*)(wT + N_IN * N_H);                    // 100096 i
    int*   part   = deg + 100096;
    int*   off    = part + 100096;                              // uses 100001
    int*   cursor = off + 100096;
    int*   bsum   = cursor + 100096;                            // 512 i
    float* wsum   = (float*)(bsum + 512);                       // 129 f

    hipMemsetAsync(deg, 0, (size_t)N_NODES * sizeof(int), stream);
    hipMemsetAsync(edata, 0, (size_t)E_PAD * sizeof(int2), stream);
    prep_kernel<<<HIST_BLKS + 33, 256, 0, stream>>>(ei, deg, Wg, wT, lW, lb, wsum);
    scan1_kernel<<<NBLK_SCAN, 256, 0, stream>>>(deg, part, bsum);
    scan3_kernel<<<NBLK_SCAN, 256, 0, stream>>>(part, bsum, deg, off, cursor);
    scatter_kernel<<<(N_EDGES + 255) / 256, 256, 0, stream>>>(ei, ew, cursor, edata);
    gemm_kernel<<<NGB, 512, 0, stream>>>(x1, x2, wT, hb);
    gcn_seg_kernel<<<N_NODES / 4, 256, 0, stream>>>(off, edata, hb, gb, pa, wsum, zout);
}

// Round 7
// 395.565 us; speedup vs baseline: 1.0101x; 1.0093x over previous
//
#include <hip/hip_runtime.h>

#define N_NODES 100000
#define N_EDGES 800000
#define N_IN    256
#define N_H     128
#define M_TOT   (2 * N_NODES)   // 200000; 16 | 100000 so waves never straddle branches
#define HB_ROW  256             // interleaved: [node][ h1(128) | h2(128) ] bf16
#define E_PAD   1200000         // max padded edges: 800000 + 4*100000

typedef __bf16 bfx8 __attribute__((ext_vector_type(8)));
typedef unsigned short u16x8 __attribute__((ext_vector_type(8)));
typedef float fx4 __attribute__((ext_vector_type(4)));

__device__ inline unsigned short f2bf(float f) {
    union { float f; unsigned u; } v; v.f = f;
    return (unsigned short)((v.u + 0x7FFF + ((v.u >> 16) & 1)) >> 16);  // RNE
}
__device__ inline float bf2f(unsigned short s) {
    union { unsigned u; float f; } v; v.u = ((unsigned)s) << 16;
    return v.f;
}

// ---------------- bf16-MFMA GEMM, both branches, interleaved output ----------
// 512 thr = 8 waves x 16 rows = 128 rows/block; W^T in LDS, XOR-swizzled.
// ALL 16 per-lane x float4 loads issued up front -> 16 in flight per wave;
// compiler inserts fine-grained vmcnt waits per j (never a full drain).
#define NGB 1563   // ceil(200000/128)

__global__ __launch_bounds__(512, 4) void gemm_kernel(
        const float* __restrict__ x1, const float* __restrict__ x2,
        const unsigned short* __restrict__ wT,     // [N_H][N_IN] bf16 bits
        unsigned short* __restrict__ hb) {         // [N_NODES][HB_ROW] bf16 bits
    __shared__ unsigned short wl[N_H * 256];       // 64 KB -> 2 blocks/CU
    const int t = threadIdx.x;
#pragma unroll
    for (int i = 0; i < 8; ++i) {                  // 4096 x 16B, coalesced
        int f  = t + i * 512;
        int n  = f >> 5;
        int kb = f & 31;
        *(u16x8*)(wl + n * 256 + ((kb ^ (n & 31)) << 3)) =
            *(const u16x8*)(wT + n * N_IN + (kb << 3));
    }
    __syncthreads();

    const int wave = t >> 6, lane = t & 63;
    const int quad = lane >> 4, l16 = lane & 15;
    const int mw = blockIdx.x * 128 + wave * 16;   // output row base, 0..199999
    if (mw >= M_TOT) return;                       // tail waves (after barrier)
    const int half = (mw < N_NODES) ? 0 : 1;
    const float* x = half ? x2 : x1;
    const int mrow = half ? mw - N_NODES : mw;

    const float* xrow = x + (size_t)(mrow + l16) * N_IN + quad * 8;

    // issue all 16 loads back-to-back: full row-of-lane in flight
    float4 xv[16];
#pragma unroll
    for (int j = 0; j < 8; ++j) {
        xv[2 * j]     = *(const float4*)(xrow + j * 32);
        xv[2 * j + 1] = *(const float4*)(xrow + j * 32 + 4);
    }

    fx4 acc[8];
#pragma unroll
    for (int c = 0; c < 8; ++c) acc[c] = (fx4){0.f, 0.f, 0.f, 0.f};

#pragma unroll
    for (int j = 0; j < 8; ++j) {
        float4 a0 = xv[2 * j], a1 = xv[2 * j + 1];
        u16x8 au;
        au[0] = f2bf(a0.x); au[1] = f2bf(a0.y); au[2] = f2bf(a0.z); au[3] = f2bf(a0.w);
        au[4] = f2bf(a1.x); au[5] = f2bf(a1.y); au[6] = f2bf(a1.z); au[7] = f2bf(a1.w);
        bfx8 af = __builtin_bit_cast(bfx8, au);
        const int kb0 = (j << 2) + quad;           // (kk/8) + quad
#pragma unroll
        for (int c = 0; c < 8; ++c) {
            int n = c * 16 + l16;
            bfx8 bf = *(const bfx8*)(wl + n * 256 + ((kb0 ^ (n & 31)) << 3));
            acc[c] = __builtin_amdgcn_mfma_f32_16x16x32_bf16(af, bf, acc[c], 0, 0, 0);
        }
    }
    // C/D: col = l16, row = quad*4 + reg; write into interleaved half
#pragma unroll
    for (int c = 0; c < 8; ++c)
#pragma unroll
        for (int r = 0; r < 4; ++r)
            hb[(size_t)(mrow + quad * 4 + r) * HB_ROW + half * N_H + c * 16 + l16] =
                f2bf(acc[c][r]);
}

// ------- prep: histogram (3125 blks) + W^T bf16 (32 blks) + wsum (1 blk) -----
#define HIST_BLKS 3125
__global__ __launch_bounds__(256) void prep_kernel(const int* __restrict__ ei,
                                                   int* __restrict__ deg,
                                                   const float* __restrict__ W,
                                                   unsigned short* __restrict__ wT,
                                                   const float* __restrict__ linW,
                                                   const float* __restrict__ linb,
                                                   float* __restrict__ wsum) {
    const int t = threadIdx.x;
    if (blockIdx.x < HIST_BLKS) {
        int e = blockIdx.x * 256 + t;
        if (e < N_EDGES) atomicAdd(deg + ei[e], 1);
    } else if (blockIdx.x < HIST_BLKS + 32) {
        int kb = (blockIdx.x - HIST_BLKS) * 8;
#pragma unroll
        for (int p = 0; p < 4; ++p) {
            int idx = p * 256 + t;
            int k = kb + (idx >> 7), n = idx & 127;
            wT[(size_t)n * N_IN + k] = f2bf(W[(size_t)k * N_H + n]);
        }
    } else {
        int j = t;
        if (j < N_H) {
            float s = 0.f;
            for (int o = 0; o < N_H; ++o) s += linW[j * N_H + o];
            wsum[j] = s;
        }
        if (j == N_H) {
            float s = 0.f;
            for (int o = 0; o < N_H; ++o) s += linb[o];
            wsum[N_H] = s;
        }
    }
}

// ---------------- scans over 4-PADDED degrees --------------------------------
__global__ __launch_bounds__(256) void scan1_kernel(const int* __restrict__ deg,
                                                    int* __restrict__ part,
                                                    int* __restrict__ bsum) {
    __shared__ int s[256];
    int g = blockIdx.x * 256 + threadIdx.x;
    int v = (g < N_NODES) ? ((deg[g] + 3) & ~3) : 0;   // pad to multiple of 4
    s[threadIdx.x] = v;
    __syncthreads();
#pragma unroll
    for (int off = 1; off < 256; off <<= 1) {
        int t = (threadIdx.x >= off) ? s[threadIdx.x - off] : 0;
        __syncthreads();
        s[threadIdx.x] += t;
        __syncthreads();
    }
    if (g < N_NODES) part[g] = s[threadIdx.x] - v;     // exclusive within block
    if (threadIdx.x == 255) bsum[blockIdx.x] = s[255]; // block total
}

#define NBLK_SCAN 391
// scan3 computes its own bsum prefix (<=391 adds) -> no separate pass
__global__ __launch_bounds__(256) void scan3_kernel(const int* __restrict__ part,
                                                    const int* __restrict__ bsum,
                                                    const int* __restrict__ deg,
                                                    int* __restrict__ off,
                                                    int* __restrict__ cursor) {
    __shared__ int red[256];
    const int t = threadIdx.x;
    int acc = 0;
    for (int j = t; j < (int)blockIdx.x; j += 256) acc += bsum[j];
    red[t] = acc;
    __syncthreads();
#pragma unroll
    for (int o = 128; o; o >>= 1) {
        if (t < o) red[t] += red[t + o];
        __syncthreads();
    }
    const int prefix = red[0];
    int g = blockIdx.x * 256 + t;
    if (g < N_NODES) {
        int o = part[g] + prefix;
        off[g] = o;
        cursor[g] = o;
        if (g == N_NODES - 1) off[N_NODES] = o + ((deg[g] + 3) & ~3);
    }
}

// ---------------- scatter: edges -> padded CSR slots -------------------------
// pad slots stay (0, 0.0f) from the edata memset -> contribute nothing.
__global__ __launch_bounds__(256) void scatter_kernel(const int* __restrict__ ei,
                                                      const float* __restrict__ ew,
                                                      int* __restrict__ cursor,
                                                      int2* __restrict__ edata) {
    int e = blockIdx.x * 256 + threadIdx.x;
    if (e >= N_EDGES) return;
    int row = ei[e];
    int pos = atomicAdd(cursor + row, 1);
    edata[pos] = make_int2(ei[N_EDGES + e] * HB_ROW, __float_as_int(ew[e]));
}

// ------- fused segment-sum SPMM + bias + PReLU + wsum-dot, BOTH branches -----
// one wave per node; half-wave per branch, 4 features/lane (ushort4 = 8B);
// one edge = one contiguous 512B wave gather. Padded segments: exact 4-unroll,
// paired int4 edata loads (16B-aligned since offsets are multiples of 4).
__global__ __launch_bounds__(256) void gcn_seg_kernel(const int* __restrict__ off,
                                                      const int2* __restrict__ edata,
                                                      const unsigned short* __restrict__ hb,
                                                      const float* __restrict__ gcn_bias,
                                                      const float* __restrict__ prelu_a,
                                                      const float* __restrict__ wsum,
                                                      float* __restrict__ zout) {
    const int wave = threadIdx.x >> 6, lane = threadIdx.x & 63;
    const int node = blockIdx.x * 4 + wave;        // 0..99999
    const int half = lane >> 5;                    // 0: branch1, 1: branch2
    const int fl   = (lane & 31) * 4;              // feature base (0..124)
    const int o8   = half * N_H + fl;              // short offset within row
    const int s = __builtin_amdgcn_readfirstlane(off[node]);
    const int e = __builtin_amdgcn_readfirstlane(off[node + 1]);
    float p0 = 0.f, p1 = 0.f, p2 = 0.f, p3 = 0.f;
    float q0 = 0.f, q1 = 0.f, q2 = 0.f, q3 = 0.f;
    for (int i = s; i < e; i += 4) {
        int4 Ea = *(const int4*)(edata + i);       // edges i, i+1
        int4 Eb = *(const int4*)(edata + i + 2);   // edges i+2, i+3
        ushort4 h0 = *(const ushort4*)(hb + Ea.x + o8);
        ushort4 h1 = *(const ushort4*)(hb + Ea.z + o8);
        ushort4 h2 = *(const ushort4*)(hb + Eb.x + o8);
        ushort4 h3 = *(const ushort4*)(hb + Eb.z + o8);
        float w0 = __int_as_float(Ea.y), w1 = __int_as_float(Ea.w);
        float w2 = __int_as_float(Eb.y), w3 = __int_as_float(Eb.w);
        p0 += w0 * bf2f(h0.x) + w1 * bf2f(h1.x);
        p1 += w0 * bf2f(h0.y) + w1 * bf2f(h1.y);
        p2 += w0 * bf2f(h0.z) + w1 * bf2f(h1.z);
        p3 += w0 * bf2f(h0.w) + w1 * bf2f(h1.w);
        q0 += w2 * bf2f(h2.x) + w3 * bf2f(h3.x);
        q1 += w2 * bf2f(h2.y) + w3 * bf2f(h3.y);
        q2 += w2 * bf2f(h2.z) + w3 * bf2f(h3.z);
        q3 += w2 * bf2f(h2.w) + w3 * bf2f(h3.w);
    }
    p0 += q0; p1 += q1; p2 += q2; p3 += q3;

    const float alpha = prelu_a[0];
    float4 gb4 = *(const float4*)(gcn_bias + fl);
    float4 ws4 = *(const float4*)(wsum + fl);
    float v0 = p0 + gb4.x, v1 = p1 + gb4.y, v2 = p2 + gb4.z, v3 = p3 + gb4.w;
    v0 = (v0 >= 0.f) ? v0 : alpha * v0;
    v1 = (v1 >= 0.f) ? v1 : alpha * v1;
    v2 = (v2 >= 0.f) ? v2 : alpha * v2;
    v3 = (v3 >= 0.f) ? v3 : alpha * v3;
    float sres = v0 * ws4.x + v1 * ws4.y + v2 * ws4.z + v3 * ws4.w;
#pragma unroll
    for (int o = 16; o; o >>= 1) sres += __shfl_down(sres, o, 32);  // within half
    if ((lane & 31) == 0)
        zout[node + half * N_NODES] = sres + wsum[128];  // wsum[128] = b_sum
}

extern "C" void kernel_launch(void* const* d_in, const int* in_sizes, int n_in,
                              void* d_out, int out_size, void* d_ws, size_t ws_size,
                              hipStream_t stream) {
    const float* x1 = (const float*)d_in[0];
    const float* x2 = (const float*)d_in[1];
    const int*   ei = (const int*)d_in[2];
    const float* ew = (const float*)d_in[3];
    const float* Wg = (const float*)d_in[4];
    const float* gb = (const float*)d_in[5];
    const float* pa = (const float*)d_in[6];
    const float* lW = (const float*)d_in[7];
    const float* lb = (const float*)d_in[8];
    float* zout = (float*)d_out;

    unsigned short* hb   = (unsigned short*)d_ws;               // 25.6M u16 (51.2MB)
    int2*  edata  = (int2*)(hb + (size_t)N_NODES * HB_ROW);     // 1.2M int2 (9.6MB)
    unsigned short* wT   = (unsigned short*)(edata + E_PAD);    // 32768 u16
    int*   deg    = (int*)(wT + N_IN * N_H);                    // 100096 i
    int*   part   = deg + 100096;
    int*   off    = part + 100096;                              // uses 100001
    int*   cursor = off + 100096;
    int*   bsum   = cursor + 100096;                            // 512 i
    float* wsum   = (float*)(bsum + 512);                       // 129 f

    hipMemsetAsync(deg, 0, (size_t)N_NODES * sizeof(int), stream);
    hipMemsetAsync(edata, 0, (size_t)E_PAD * sizeof(int2), stream);
    prep_kernel<<<HIST_BLKS + 33, 256, 0, stream>>>(ei, deg, Wg, wT, lW, lb, wsum);
    scan1_kernel<<<NBLK_SCAN, 256, 0, stream>>>(deg, part, bsum);
    scan3_kernel<<<NBLK_SCAN, 256, 0, stream>>>(part, bsum, deg, off, cursor);
    scatter_kernel<<<(N_EDGES + 255) / 256, 256, 0, stream>>>(ei, ew, cursor, edata);
    gemm_kernel<<<NGB, 512, 0, stream>>>(x1, x2, wT, hb);
    gcn_seg_kernel<<<N_NODES / 4, 256, 0, stream>>>(off, edata, hb, gb, pa, wsum, zout);
}